// Round 1
// baseline (491.691 us; speedup 1.0000x reference)
//
#include <hip/hip_runtime.h>

typedef unsigned short u16;
typedef unsigned int u32;

using bf16x8 = __attribute__((ext_vector_type(8))) __bf16;
using f32x4  = __attribute__((ext_vector_type(4))) float;
using u16x8  = __attribute__((ext_vector_type(8))) u16;

#define BB 4
#define TT 4096
#define DD 2048
#define MM 16384
#define KK 2048
#define NCHUNK 16
#define CLEN 256

__device__ __forceinline__ u16 f2bf(float f) {
    u32 u = __float_as_uint(f);
    u32 r = (u + 0x7FFFu + ((u >> 16) & 1u)) >> 16;
    return (u16)r;
}

__device__ __forceinline__ void gload_lds16(const void* g, void* l) {
    __builtin_amdgcn_global_load_lds(
        (const __attribute__((address_space(1))) void*)g,
        (__attribute__((address_space(3))) void*)l, 16, 0, 0);
}

// ---------------- fp32 -> bf16 convert (8 elems/thread) ----------------
__global__ __launch_bounds__(256) void cvt_kernel(const float* __restrict__ in,
                                                  u16* __restrict__ out, int n8) {
    int i = blockIdx.x * 256 + threadIdx.x;
    if (i >= n8) return;
    const f32x4* p = (const f32x4*)in + (size_t)i * 2;
    f32x4 a = p[0], b = p[1];
    u16x8 o;
    o[0] = f2bf(a[0]); o[1] = f2bf(a[1]); o[2] = f2bf(a[2]); o[3] = f2bf(a[3]);
    o[4] = f2bf(b[0]); o[5] = f2bf(b[1]); o[6] = f2bf(b[2]); o[7] = f2bf(b[3]);
    *((u16x8*)out + i) = o;
}

// ---------------- fused dual GEMM + gate epilogue ----------------
// gate_in[m,e]  = sum_k x[m,k] * W_in[e,k]
// gate_rec[m,e] = sum_k x[m,k] * W_gate[e,k]
// g  = 8*softplus(lam[e])*sigmoid(gate_rec+b_gate)
// xb = sqrt(1-exp(-2g)+1e-6)*sigmoid(gate_in+b_in)*x[m,e]
// pair[m,e] = bf16(g) | bf16(xb)<<16
#define BM 128
#define BN 128
#define BKg 32

__global__ __launch_bounds__(512) void gemm_dual(
    const u16* __restrict__ xb, const u16* __restrict__ wib, const u16* __restrict__ wgb,
    const float* __restrict__ xf,
    const float* __restrict__ b_in, const float* __restrict__ b_gate,
    const float* __restrict__ lam, u32* __restrict__ pair)
{
    __shared__ u16 As[BM * BKg];
    __shared__ u16 Bi[BN * BKg];
    __shared__ u16 Bg[BN * BKg];

    int tid = threadIdx.x;
    int bid = blockIdx.x;
    // XCD-aware swizzle (2048 % 8 == 0, simple form is bijective)
    int cpx = gridDim.x >> 3;
    int swz = (bid & 7) * cpx + (bid >> 3);
    int et = swz & 15;   // 16 e-tiles (fast-varying -> same x-panel on same XCD)
    int mt = swz >> 4;   // 128 m-tiles

    size_t m0 = (size_t)mt * BM;
    size_t e0 = (size_t)et * BN;

    int lane = tid & 63;
    int wid = tid >> 6;   // 0..7
    int wr  = wid >> 2;   // 0..1 -> m offset wr*64
    int wc  = wid & 3;    // 0..3 -> e offset wc*32

    // staging map: thread -> (row = tid/4, 16B segment = tid%4)
    int srow = tid >> 2;
    int skp  = (tid & 3) << 3;
    const u16* ga = xb  + (m0 + srow) * KK + skp;
    const u16* gi = wib + (e0 + srow) * KK + skp;
    const u16* gg = wgb + (e0 + srow) * KK + skp;
    u16* la = &As[tid * 8];
    u16* li = &Bi[tid * 8];
    u16* lg = &Bg[tid * 8];

    f32x4 accI[4][2], accG[4][2];
#pragma unroll
    for (int i = 0; i < 4; i++)
#pragma unroll
        for (int j = 0; j < 2; j++) {
            accI[i][j] = (f32x4){0.f, 0.f, 0.f, 0.f};
            accG[i][j] = (f32x4){0.f, 0.f, 0.f, 0.f};
        }

    int rowIn16 = lane & 15;
    int ksel = (lane >> 4) << 3;   // 0,8,16,24

    for (int k0 = 0; k0 < KK; k0 += BKg) {
        gload_lds16(ga, la);
        gload_lds16(gi, li);
        gload_lds16(gg, lg);
        ga += BKg; gi += BKg; gg += BKg;
        __syncthreads();

        bf16x8 aF[4], iF[2], gF[2];
#pragma unroll
        for (int mi = 0; mi < 4; mi++)
            aF[mi] = *(const bf16x8*)&As[(wr * 64 + mi * 16 + rowIn16) * BKg + ksel];
#pragma unroll
        for (int ni = 0; ni < 2; ni++) {
            iF[ni] = *(const bf16x8*)&Bi[(wc * 32 + ni * 16 + rowIn16) * BKg + ksel];
            gF[ni] = *(const bf16x8*)&Bg[(wc * 32 + ni * 16 + rowIn16) * BKg + ksel];
        }
#pragma unroll
        for (int mi = 0; mi < 4; mi++)
#pragma unroll
            for (int ni = 0; ni < 2; ni++) {
                accI[mi][ni] = __builtin_amdgcn_mfma_f32_16x16x32_bf16(aF[mi], iF[ni], accI[mi][ni], 0, 0, 0);
                accG[mi][ni] = __builtin_amdgcn_mfma_f32_16x16x32_bf16(aF[mi], gF[ni], accG[mi][ni], 0, 0, 0);
            }
        __syncthreads();
    }

    // epilogue: per-lane column params
    float spl[2], biv[2], bgv[2];
    size_t ecol[2];
#pragma unroll
    for (int ni = 0; ni < 2; ni++) {
        size_t e = e0 + wc * 32 + ni * 16 + rowIn16;
        ecol[ni] = e;
        spl[ni] = 8.0f * log1pf(__expf(lam[e]));
        biv[ni] = b_in[e];
        bgv[ni] = b_gate[e];
    }
    int rbase = (lane >> 4) * 4;
#pragma unroll
    for (int mi = 0; mi < 4; mi++) {
#pragma unroll
        for (int r = 0; r < 4; r++) {
            size_t m = m0 + wr * 64 + mi * 16 + rbase + r;
#pragma unroll
            for (int ni = 0; ni < 2; ni++) {
                size_t e = ecol[ni];
                float ig = accI[mi][ni][r] + biv[ni];
                float rg = accG[mi][ni][r] + bgv[ni];
                float sigr = 1.f / (1.f + __expf(-rg));
                float g = spl[ni] * sigr;
                float beta = sqrtf(1.f - __expf(-2.f * g) + 1e-6f);
                float xv = xf[m * DD + e];
                float xbeta = beta * (1.f / (1.f + __expf(-ig))) * xv;
                u32 pk = (u32)f2bf(g) | (((u32)f2bf(xbeta)) << 16);
                pair[m * DD + e] = pk;
            }
        }
    }
}

// ---------------- chunked scan ----------------
// pair layout [B,T,D]: low16 = bf16(g), high16 = bf16(xbeta); alpha = exp(-g)
__global__ __launch_bounds__(256) void scanA(const u32* __restrict__ pair,
                                             float* __restrict__ aggG,
                                             float* __restrict__ aggB) {
    int gid = blockIdx.x * 256 + threadIdx.x;   // 131072
    int e = gid & (DD - 1);
    int rest = gid >> 11;     // 0..63
    int b = rest & 3;
    int c = rest >> 2;        // 0..15
    const u32* p = pair + ((size_t)(b * TT + c * CLEN)) * DD + e;
    float gsum = 0.f, h = 0.f;
#pragma unroll 4
    for (int t = 0; t < CLEN; ++t) {
        u32 v = *p; p += DD;
        float gf = __uint_as_float(v << 16);
        float xbv = __uint_as_float(v & 0xFFFF0000u);
        gsum += gf;
        h = fmaf(__expf(-gf), h, xbv);
    }
    int idx = ((b * NCHUNK + c) << 11) | e;
    aggG[idx] = gsum;
    aggB[idx] = h;
}

__global__ __launch_bounds__(256) void scanB(const float* __restrict__ aggG,
                                             const float* __restrict__ aggB,
                                             float* __restrict__ carry) {
    int gid = blockIdx.x * 256 + threadIdx.x;   // 8192
    int e = gid & (DD - 1);
    int b = gid >> 11;
    float h = 0.f;
#pragma unroll
    for (int c = 0; c < NCHUNK; ++c) {
        int idx = ((b * NCHUNK + c) << 11) | e;
        carry[idx] = h;
        h = fmaf(__expf(-aggG[idx]), h, aggB[idx]);
    }
}

__global__ __launch_bounds__(256) void scanC(const u32* __restrict__ pair,
                                             const float* __restrict__ carry,
                                             float* __restrict__ out) {
    int gid = blockIdx.x * 256 + threadIdx.x;   // 131072
    int e = gid & (DD - 1);
    int rest = gid >> 11;
    int b = rest & 3;
    int c = rest >> 2;
    const u32* p = pair + ((size_t)(b * TT + c * CLEN)) * DD + e;
    float* o = out + ((size_t)(b * TT + c * CLEN)) * DD + e;
    float h = carry[((b * NCHUNK + c) << 11) | e];
#pragma unroll 4
    for (int t = 0; t < CLEN; ++t) {
        u32 v = *p; p += DD;
        float gf = __uint_as_float(v << 16);
        float xbv = __uint_as_float(v & 0xFFFF0000u);
        h = fmaf(__expf(-gf), h, xbv);
        *o = h; o += DD;
    }
}

extern "C" void kernel_launch(void* const* d_in, const int* in_sizes, int n_in,
                              void* d_out, int out_size, void* d_ws, size_t ws_size,
                              hipStream_t stream) {
    const float* x      = (const float*)d_in[0];
    const float* W_in   = (const float*)d_in[1];
    const float* b_in   = (const float*)d_in[2];
    const float* W_gate = (const float*)d_in[3];
    const float* b_gate = (const float*)d_in[4];
    const float* lam    = (const float*)d_in[5];
    float* out = (float*)d_out;

    char* ws = (char*)d_ws;
    u16* xb   = (u16*)(ws);                  // 67,108,864 B
    u16* wib  = (u16*)(ws + 67108864);       //  8,388,608 B
    u16* wgb  = (u16*)(ws + 75497472);       //  8,388,608 B
    u32* pair = (u32*)(ws + 83886080);       // 134,217,728 B
    float* aggG  = (float*)(ws + 218103808); // 524,288 B
    float* aggB  = (float*)(ws + 218628096); // 524,288 B
    float* carry = (float*)(ws + 219152384); // 524,288 B

    cvt_kernel<<<16384, 256, 0, stream>>>(x, xb, MM * KK / 8);
    cvt_kernel<<<2048, 256, 0, stream>>>(W_in, wib, DD * KK / 8);
    cvt_kernel<<<2048, 256, 0, stream>>>(W_gate, wgb, DD * KK / 8);
    gemm_dual<<<(MM / BM) * (DD / BN), 512, 0, stream>>>(xb, wib, wgb, x, b_in, b_gate, lam, pair);
    scanA<<<BB * DD * NCHUNK / 256, 256, 0, stream>>>(pair, aggG, aggB);
    scanB<<<BB * DD / 256, 256, 0, stream>>>(aggG, aggB, carry);
    scanC<<<BB * DD * NCHUNK / 256, 256, 0, stream>>>(pair, carry, out);
}